// Round 7
// baseline (458.811 us; speedup 1.0000x reference)
//
#include <hip/hip_runtime.h>
#include <math.h>
#include <type_traits>

// ---------- bf16 helpers (intermediate buffers only; I/O is fp32) ----------

__device__ __forceinline__ float bf2f(unsigned short u) {
    union { unsigned int i; float f; } v; v.i = ((unsigned int)u) << 16; return v.f;
}
__device__ __forceinline__ unsigned short f2bf(float f) {
    union { float f_; unsigned int i; } v; v.f_ = f;
    unsigned int x = v.i;
    return (unsigned short)((x + 0x7fffu + ((x >> 16) & 1u)) >> 16);  // RNE
}
__device__ __forceinline__ float sigm(float x) { return 1.f / (1.f + expf(-x)); }

typedef __attribute__((ext_vector_type(8))) short short8;
typedef __attribute__((ext_vector_type(16))) float f32x16;

__device__ __forceinline__ void nt_store8(unsigned short* p, ushort4 o) {
    unsigned long long ob;
    __builtin_memcpy(&ob, &o, 8);
    __builtin_nontemporal_store(ob, (unsigned long long*)p);
}

// ---------------- fused init ----------------

__global__ void k_init(int* __restrict__ indeg, int* __restrict__ cursor,
                       int* __restrict__ gstart, int* __restrict__ gend,
                       float* __restrict__ pooled, int N) {
    int i = blockIdx.x * 256 + threadIdx.x;
    if (i < N) indeg[i] = 0;
    else if (i < 2 * N) cursor[i - N] = 0;
    else if (i < 2 * N + 64) gstart[i - 2 * N] = 0;
    else if (i < 2 * N + 128) gend[i - 2 * N - 64] = 0;
    else if (i < 2 * N + 128 + 64 * 512) pooled[i - 2 * N - 128] = 0.f;
}

// ---------------- weight prep: fragment-major Wf for 32x32x16 MFMA ----------------
// (W1 removed: layer 1 is a fused VALU GEMV inside k_aggL1f)

template <int K, int NC>
__device__ __forceinline__ void prep_elem(const float* __restrict__ W,
                                          unsigned short* __restrict__ Wf, int idx) {
    constexpr int S = K / 16;
    int lane = idx & 63;
    int ts = idx >> 6;
    int s = ts % S, t = ts / S;
    int n = t * 32 + (lane & 31);
    int kb = s * 16 + (lane >> 5) * 8;
    short8 o;
    #pragma unroll
    for (int j = 0; j < 8; ++j) o[j] = (short)f2bf(W[(size_t)(kb + j) * NC + n]);
    *(short8*)(Wf + (size_t)idx * 8) = o;
}

__global__ void k_count(const int* __restrict__ dst, int* __restrict__ indeg, int E,
                        const float* __restrict__ W2, unsigned short* __restrict__ Wf2,
                        const float* __restrict__ W3, unsigned short* __restrict__ Wf3) {
    constexpr int P2 = 128 * 256 / 8, P3 = 256 * 512 / 8;
    int i = blockIdx.x * 256 + threadIdx.x;
    if (i < E) atomicAdd(&indeg[dst[i]], 1);
    if (i < P2) prep_elem<128, 256>(W2, Wf2, i);
    else if (i < P2 + P3) prep_elem<256, 512>(W3, Wf3, i - P2);
}

// ---------------- scan + dinv + prescaled xs = bf16(x*dinv) ----------------

__global__ __launch_bounds__(1024) void k_scan1(const int* __restrict__ in, int* __restrict__ out,
                                                int* __restrict__ bsum, float* __restrict__ dinv,
                                                const float* __restrict__ x,
                                                unsigned short* __restrict__ xs,
                                                int N) {
    __shared__ int sd[1024];
    __shared__ float sdv[1024];
    int tid = threadIdx.x;
    int i = blockIdx.x * 1024 + tid;
    int v = (i < N) ? in[i] : 0;
    float dv = rsqrtf((float)v + 1.0f);
    if (i < N) dinv[i] = dv;
    sdv[tid] = dv;
    sd[tid] = v;
    __syncthreads();
    for (int s = 1; s < 1024; s <<= 1) {
        int t = (tid >= s) ? sd[tid - s] : 0;
        __syncthreads();
        sd[tid] += t;
        __syncthreads();
    }
    if (i < N) out[i] = sd[tid] - v;
    if (tid == 1023) bsum[blockIdx.x] = sd[1023];
    // prescale: xs[node] = bf16(x[node] * dinv[node]); 8 ushort4 chunks/node
    int base = blockIdx.x * 1024;
    const float4* x4 = (const float4*)x;
    ushort4* xs4 = (ushort4*)xs;
    #pragma unroll
    for (int rep = 0; rep < 8; ++rep) {
        int j = rep * 1024 + tid;            // [0, 8192): 8 chunks per node
        int node = base + (j >> 3);
        if (node < N) {
            float4 t = x4[(size_t)base * 8 + j];
            float s = sdv[j >> 3];
            ushort4 o;
            o.x = f2bf(t.x * s); o.y = f2bf(t.y * s);
            o.z = f2bf(t.z * s); o.w = f2bf(t.w * s);
            xs4[(size_t)base * 8 + j] = o;   // normal store: random-gathered next
        }
    }
}

// scan3 with folded block-sum reduction (R22: k_scan2 dispatch removed).
// Each block locally reduces bsum[0..nb) for its prefix and the grand total.
__global__ __launch_bounds__(1024) void k_scan3(int* __restrict__ off, const int* __restrict__ bsum,
                                                const int* __restrict__ batch,
                                                int* __restrict__ gstart, int* __restrict__ gend,
                                                int N, int nb) {
    __shared__ int red[32];
    int tid = threadIdx.x, lane = tid & 63, wid = tid >> 6;
    int bid = blockIdx.x;
    int v  = (tid < nb) ? bsum[tid] : 0;     // nb <= 128 < 1024
    int vb = (tid < bid) ? v : 0;
    #pragma unroll
    for (int msk = 1; msk <= 32; msk <<= 1) {
        v  += __shfl_xor(v,  msk, 64);
        vb += __shfl_xor(vb, msk, 64);
    }
    if (lane == 0) { red[wid * 2] = v; red[wid * 2 + 1] = vb; }
    __syncthreads();
    int sAll = 0, sBefore = 0;
    #pragma unroll
    for (int u = 0; u < 16; ++u) { sAll += red[u * 2]; sBefore += red[u * 2 + 1]; }

    int i = bid * 1024 + tid;
    if (i < N) {
        off[i] += sBefore;
        int g = batch[i];
        if (i == 0 || batch[i - 1] != g) gstart[g] = i;
        if (i == N - 1 || batch[i + 1] != g) gend[g] = i + 1;
    } else if (i == N) {
        off[N] = sAll;
    }
}

// fill: csrc only (R20: edge weights folded into prescaled features)
__global__ void k_fill(const int* __restrict__ src, const int* __restrict__ dst,
                       const int* __restrict__ off, int* __restrict__ cursor,
                       int* __restrict__ csrc, int E) {
    int i = blockIdx.x * 256 + threadIdx.x;
    if (i >= E) return;
    int d = dst[i];
    int p = off[d] + atomicAdd(&cursor[d], 1);
    csrc[p] = src[i];
}

// ---------------- layer 1: fused aggregation + GEMV (R22, R23 staging fix) --
// agg phase identical to old k_aggL1; then lanes 0-7 publish the 32-float agg
// row to per-wave LDS (intra-wave dep, no barrier), all 64 lanes GEMV 2 cols
// each from LDS-staged fp32 W1 (16 KB/block), relu * dinv, ushort2 store.
// R23: staging loop stride was i*4096 (OOB LDS write + 3/4 garbage weights,
// absmax 2.3e-3); correct stride is i*1024 (256 thr x float4 per pass).

__global__ __launch_bounds__(256) void k_aggL1f(
        const unsigned short* __restrict__ Hin,   // xs: N x 32 bf16 (prescaled)
        const float* __restrict__ dinv,
        const int* __restrict__ off, const int* __restrict__ csrc,
        const float* __restrict__ W1, const float* __restrict__ b1,
        unsigned short* __restrict__ out, int N) { // out: N x 128 bf16 (prescaled)
    constexpr int F = 32;
    __shared__ float sW[32 * 128];
    __shared__ float srow[4][32];
    int tid = threadIdx.x;
    #pragma unroll
    for (int i = 0; i < 4; ++i) {
        int j = i * 1024 + tid * 4;          // [0, 4096) exactly
        *(float4*)&sW[j] = *(const float4*)&W1[j];
    }
    __syncthreads();

    int w = tid >> 6;
    int wv = (int)((blockIdx.x * 256u + tid) >> 6);
    if (wv >= N) return;                     // no barriers after this point
    int lane = tid & 63;
    int grp = lane >> 3;
    int cl = (lane & 7) * 4;
    int s0 = off[wv], s1 = off[wv + 1];
    int L = s1 - s0;
    float corr = 1.0f - (float)(((L + 7) & ~7) - L);
    float dn = dinv[wv];
    float acc[4] = {0.f, 0.f, 0.f, 0.f};
    for (int e = s0; e < s1; e += 8) {
        int ee = e + grp;
        int ix = csrc[ee];                   // padded alloc: safe past s1
        int idx = (ee < s1) ? ix : wv;       // tail gathers own row
        ushort4 v = *(const ushort4*)(Hin + (size_t)idx * F + cl);
        acc[0] += bf2f(v.x); acc[1] += bf2f(v.y);
        acc[2] += bf2f(v.z); acc[3] += bf2f(v.w);
    }
    #pragma unroll
    for (int msk = 8; msk <= 32; msk <<= 1) {
        acc[0] += __shfl_xor(acc[0], msk, 64);
        acc[1] += __shfl_xor(acc[1], msk, 64);
        acc[2] += __shfl_xor(acc[2], msk, 64);
        acc[3] += __shfl_xor(acc[3], msk, 64);
    }
    ushort4 sv = *(const ushort4*)(Hin + (size_t)wv * F + cl);
    if (lane < 8) {
        float4 a;
        a.x = (acc[0] + corr * bf2f(sv.x)) * dn;
        a.y = (acc[1] + corr * bf2f(sv.y)) * dn;
        a.z = (acc[2] + corr * bf2f(sv.z)) * dn;
        a.w = (acc[3] + corr * bf2f(sv.w)) * dn;
        *(float4*)&srow[w][cl] = a;          // cl = lane*4 for lane<8
    }
    // GEMV: 2 output cols per lane; srow read is wave-uniform (broadcast)
    float2 bv = *(const float2*)&b1[2 * lane];
    float c0 = bv.x, c1 = bv.y;
    #pragma unroll
    for (int k = 0; k < 32; ++k) {
        float ak = srow[w][k];
        float2 wk = *(const float2*)&sW[k * 128 + 2 * lane];
        c0 = fmaf(ak, wk.x, c0);
        c1 = fmaf(ak, wk.y, c1);
    }
    c0 = fmaxf(c0, 0.f) * dn;                // prescale for next aggregation
    c1 = fmaxf(c1, 0.f) * dn;
    ushort2 o; o.x = f2bf(c0); o.y = f2bf(c1);
    *(ushort2*)(out + (size_t)wv * 128 + 2 * lane) = o;   // gathered next: keep in L2
}

// ---------------- aggregation L2/L3: pure unweighted sum of prescaled rows --
// agg[d] = dinv[d] * (sum_src hs[src] + hs[d]); OOB tail slots gather the
// node's own row, corrected exactly via corr = 1 - pad. csrc is alloc-padded.
// Outputs NT-stored (consumer = streaming GEMM read; keep L2 for gathers).

// L2: F=128 bf16, pair structure (2 edges per half-wave, ushort4 loads)
__global__ __launch_bounds__(256) void k_aggL2(
        const unsigned short* __restrict__ Hin, const float* __restrict__ dinv,
        const int* __restrict__ off, const int* __restrict__ csrc,
        unsigned short* __restrict__ out, int N) {
    constexpr int F = 128;
    int wv = __builtin_amdgcn_readfirstlane(
        (int)((blockIdx.x * 256u + threadIdx.x) >> 6));
    if (wv >= N) return;
    int lane = threadIdx.x & 63;
    int half = lane >> 5;
    int fb = (lane & 31) * 4;
    int s0 = off[wv], s1 = off[wv + 1];
    int L = s1 - s0;
    float corrTot = 1.0f - (float)(((L + 15) & ~15) - L);
    float acc[4] = {0.f, 0.f, 0.f, 0.f};

    for (int e = s0; e < s1; e += 16) {
        int idx[8];
        #pragma unroll
        for (int j = 0; j < 8; ++j) {
            int ee = e + j * 2 + half;
            int ix = csrc[ee];
            idx[j] = (ee < s1) ? ix : wv;
        }
        ushort4 d0[8];
        #pragma unroll
        for (int j = 0; j < 8; ++j)
            d0[j] = *(const ushort4*)(Hin + (size_t)idx[j] * F + fb);
        #pragma unroll
        for (int j = 0; j < 8; ++j) {
            acc[0] += bf2f(d0[j].x); acc[1] += bf2f(d0[j].y);
            acc[2] += bf2f(d0[j].z); acc[3] += bf2f(d0[j].w);
        }
    }
    #pragma unroll
    for (int k = 0; k < 4; ++k) acc[k] += __shfl_xor(acc[k], 32, 64);

    if (half == 0) {
        float dn = dinv[wv];
        ushort4 sv = *(const ushort4*)(Hin + (size_t)wv * F + fb);
        ushort4 o;
        o.x = f2bf((acc[0] + corrTot * bf2f(sv.x)) * dn);
        o.y = f2bf((acc[1] + corrTot * bf2f(sv.y)) * dn);
        o.z = f2bf((acc[2] + corrTot * bf2f(sv.z)) * dn);
        o.w = f2bf((acc[3] + corrTot * bf2f(sv.w)) * dn);
        nt_store8(out + (size_t)wv * F + fb, o);
    }
}

// L3: F=256 bf16, pair structure (2 edges per half-wave, short8 loads)
__global__ __launch_bounds__(256) void k_aggL3pair(
        const unsigned short* __restrict__ Hin, const float* __restrict__ dinv,
        const int* __restrict__ off, const int* __restrict__ csrc,
        unsigned short* __restrict__ out, int N) {
    constexpr int F = 256;
    int wv = __builtin_amdgcn_readfirstlane(
        (int)((blockIdx.x * 256u + threadIdx.x) >> 6));
    if (wv >= N) return;
    int lane = threadIdx.x & 63;
    int half = lane >> 5;
    int fb = (lane & 31) * 8;
    int s0 = off[wv], s1 = off[wv + 1];
    int L = s1 - s0;
    float corrTot = 1.0f - (float)(((L + 15) & ~15) - L);
    float acc[8];
    #pragma unroll
    for (int k = 0; k < 8; ++k) acc[k] = 0.f;

    for (int e = s0; e < s1; e += 16) {
        int idx[8];
        #pragma unroll
        for (int j = 0; j < 8; ++j) {
            int ee = e + j * 2 + half;
            int ix = csrc[ee];               // padded alloc: safe past s1
            idx[j] = (ee < s1) ? ix : wv;
        }
        short8 d0[8];
        #pragma unroll
        for (int j = 0; j < 8; ++j)
            d0[j] = *(const short8*)(Hin + (size_t)idx[j] * F + fb);
        #pragma unroll
        for (int j = 0; j < 8; ++j) {
            #pragma unroll
            for (int k = 0; k < 8; ++k)
                acc[k] += bf2f((unsigned short)d0[j][k]);
        }
    }
    #pragma unroll
    for (int k = 0; k < 8; ++k) acc[k] += __shfl_xor(acc[k], 32, 64);

    if (half == 0) {
        float dn = dinv[wv];
        short8 selfv = *(const short8*)(Hin + (size_t)wv * F + fb);
        short8 o;
        #pragma unroll
        for (int k = 0; k < 8; ++k)
            o[k] = (short)f2bf((acc[k] + corrTot * bf2f((unsigned short)selfv[k])) * dn);
        __builtin_nontemporal_store(o, (short8*)(out + (size_t)wv * F + fb));
    }
}

// ---------------- MFMA GEMM: LDS-staged A (swizzled), coalesced B -------------
// POOL=0 epilogue stores relu(.)*dinv[row] (prescaled for next aggregation).
// POOL=1 epilogue: atomic-free register pooling (R18) into partial[tile][2][512].

template <int K, int NC, int POOL>
__device__ __forceinline__ void gemm_body(
        const unsigned short* __restrict__ A, const unsigned short* __restrict__ Wf,
        const float* __restrict__ bias, const float* __restrict__ dinv,
        unsigned short* __restrict__ C,
        float* __restrict__ pooled, float* __restrict__ partial,
        int* __restrict__ gtile, const int* __restrict__ batch, int M) {
    constexpr int S = K / 16;
    constexpr int CPR = K / 8;
    constexpr int NT = NC / 32;
    __shared__ unsigned short sA[64 * K];
    __shared__ int sbat[POOL ? 64 : 1];
    __shared__ float sdv[POOL ? 1 : 64];
    int tid = threadIdx.x, lane = tid & 63, w = tid >> 6;
    int q = lane >> 5, m = lane & 31;
    int row0 = blockIdx.x * 64;

    if (tid < 64) {
        int rr = row0 + tid; if (rr > M - 1) rr = M - 1;
        if (POOL) sbat[tid] = batch[rr];
        else      sdv[tid] = dinv[rr];
    }

    #pragma unroll
    for (int i = 0; i < (64 * CPR) / 256; ++i) {
        int g = i * 256 + tid;
        int mm = g / CPR, kc = g % CPR;
        int grow = row0 + mm; if (grow > M - 1) grow = M - 1;
        short8 v = *(const short8*)(A + (size_t)grow * K + kc * 8);
        int xm = (CPR >= 8) ? (mm & 7) : ((mm >> 1) & 3);
        *(short8*)(sA + (size_t)(mm * CPR + (kc ^ xm)) * 8) = v;
    }
    __syncthreads();

    int gmin = 0; bool fast = false;
    unsigned int selMask = 0;   // bit (half*16+j): row belongs to gmin+1 (not gmin)
    if (POOL) {
        gmin = sbat[0];
        fast = (sbat[63] - gmin) <= 1;
        if (tid == 0) gtile[blockIdx.x] = gmin;
        #pragma unroll
        for (int half = 0; half < 2; ++half) {
            #pragma unroll
            for (int j = 0; j < 16; ++j) {
                int rloc = half * 32 + (j & 3) + 8 * (j >> 2) + 4 * q;
                if (sbat[rloc] != gmin) selMask |= 1u << (half * 16 + j);
            }
        }
    }

    const short8* Wf8 = (const short8*)Wf;
    for (int t = w; t < NT; t += 4) {
        short8 bF[S];
        #pragma unroll
        for (int s = 0; s < S; ++s) bF[s] = Wf8[(t * S + s) * 64 + lane];
        int colBase = t * 32 + m;
        float bv = bias[colBase];
        float p0 = 0.f, p1 = 0.f;   // register pooling: graph gmin / gmin+1
        #pragma unroll
        for (int half = 0; half < 2; ++half) {
            int mrow = half * 32 + m;
            int xm = (CPR >= 8) ? (mrow & 7) : ((mrow >> 1) & 3);
            f32x16 acc;
            #pragma unroll
            for (int j = 0; j < 16; ++j) acc[j] = 0.f;
            #pragma unroll
            for (int s = 0; s < S; ++s) {
                int kc = s * 2 + q;
                short8 aF = *(const short8*)(sA + (size_t)(mrow * CPR + (kc ^ xm)) * 8);
                acc = __builtin_amdgcn_mfma_f32_32x32x16_bf16(aF, bF[s], acc, 0, 0, 0);
            }
            #pragma unroll
            for (int j = 0; j < 16; ++j) {
                int rloc = half * 32 + (j & 3) + 8 * (j >> 2) + 4 * q;
                int row = row0 + rloc;
                if (row < M) {
                    float v = fmaxf(acc[j] + bv, 0.f);
                    if (POOL) {
                        if (fast) {
                            bool sel = (selMask >> (half * 16 + j)) & 1u;
                            p0 += sel ? 0.f : v;
                            p1 += sel ? v : 0.f;
                        } else {
                            // >2 graphs in one 64-row tile: essentially impossible
                            // for this input (nodes/graph ~1563); correctness path.
                            atomicAdd(&pooled[(size_t)sbat[rloc] * NC + colBase], v);
                        }
                    } else {
                        C[(size_t)row * NC + colBase] = f2bf(v * sdv[rloc]);
                    }
                }
            }
        }
        if (POOL) {
            // lanes l and l+32 share colBase -> combine, then one plain store
            p0 += __shfl_xor(p0, 32, 64);
            p1 += __shfl_xor(p1, 32, 64);
            if (q == 0) {
                partial[((size_t)blockIdx.x * 2 + 0) * NC + colBase] = p0;
                partial[((size_t)blockIdx.x * 2 + 1) * NC + colBase] = p1;
            }
        }
    }
}

__global__ __launch_bounds__(256, 2) void k_gemmL2(
        const unsigned short* __restrict__ A, const unsigned short* __restrict__ Wf,
        const float* __restrict__ bias, const float* __restrict__ dinv,
        unsigned short* __restrict__ C, int M) {
    gemm_body<128, 256, 0>(A, Wf, bias, dinv, C, nullptr, nullptr, nullptr, nullptr, M);
}

__global__ __launch_bounds__(256, 2) void k_gemmL3pool(
        const unsigned short* __restrict__ A, const unsigned short* __restrict__ Wf,
        const float* __restrict__ bias, float* __restrict__ pooled,
        float* __restrict__ partial, int* __restrict__ gtile,
        const int* __restrict__ batch, int M) {
    gemm_body<256, 512, 1>(A, Wf, bias, nullptr, nullptr, pooled, partial, gtile, batch, M);
}

// ---------------- head, split for parallelism (R19) ----------------

// partial-tile reduce -> normalized mean xmean[64][512]
__global__ __launch_bounds__(256) void k_pool(
        const float* __restrict__ pooled, const float* __restrict__ partial,
        const int* __restrict__ gtile,
        const int* __restrict__ gstart, const int* __restrict__ gend,
        float* __restrict__ xmean) {
    int g = blockIdx.x, tid = threadIdx.x;
    int gs = gstart[g], ge = gend[g];
    float inv = 1.f / fmaxf((float)(ge - gs), 1.f);
    float a0 = pooled[g * 512 + tid];
    float a1 = pooled[g * 512 + 256 + tid];
    if (ge > gs) {
        int t0 = gs >> 6, t1 = (ge - 1) >> 6;
        for (int t = t0; t <= t1; ++t) {
            unsigned int slot = (unsigned int)(g - gtile[t]);
            if (slot < 2u) {
                const float* p = partial + ((size_t)t * 2 + slot) * 512;
                a0 += p[tid];
                a1 += p[tid + 256];
            }
        }
    }
    xmean[g * 512 + tid]       = a0 * inv;
    xmean[g * 512 + 256 + tid] = a1 * inv;
}

__device__ __forceinline__ float dot8(const float* __restrict__ w,
                                      float4 x0, float4 x1) {
    float4 a = *(const float4*)w, b = *(const float4*)(w + 4);
    return a.x * x0.x + a.y * x0.y + a.z * x0.z + a.w * x0.w +
           b.x * x1.x + b.y * x1.y + b.z * x1.z + b.w * x1.w;
}
__device__ __forceinline__ float dot4(const float* __restrict__ w, float4 x) {
    float4 a = *(const float4*)w;
    return a.x * x.x + a.y * x.y + a.z * x.z + a.w * x.w;
}

// LSTM0: one wave per (graph, hidden unit); gates i,g,o (f dead: c0=0)
__global__ __launch_bounds__(256) void k_lstm0(
        const float* __restrict__ xmean, const float* __restrict__ Wih0,
        const float* __restrict__ bih0, const float* __restrict__ bhh0,
        float* __restrict__ h1) {
    int wid = (int)((blockIdx.x * 256u + threadIdx.x) >> 6);  // [0, 16384)
    int lane = threadIdx.x & 63;
    int g = wid >> 8, hu = wid & 255;
    int k0 = lane * 8;
    const float* xp = xmean + g * 512 + k0;
    float4 x0 = *(const float4*)xp, x1 = *(const float4*)(xp + 4);
    float ai = dot8(Wih0 + (size_t)hu * 512 + k0, x0, x1);
    float ag = dot8(Wih0 + (size_t)(hu + 512) * 512 + k0, x0, x1);
    float ao = dot8(Wih0 + (size_t)(hu + 768) * 512 + k0, x0, x1);
    #pragma unroll
    for (int msk = 32; msk >= 1; msk >>= 1) {
        ai += __shfl_xor(ai, msk, 64);
        ag += __shfl_xor(ag, msk, 64);
        ao += __shfl_xor(ao, msk, 64);
    }
    if (lane == 0) {
        ai += bih0[hu]       + bhh0[hu];
        ag += bih0[hu + 512] + bhh0[hu + 512];
        ao += bih0[hu + 768] + bhh0[hu + 768];
        float c0 = sigm(ai) * tanhf(ag);
        h1[g * 256 + hu] = sigm(ao) * tanhf(c0);
    }
}

// LSTM1: one wave per (graph, hidden unit), K=256
__global__ __launch_bounds__(256) void k_lstm1(
        const float* __restrict__ h1, const float* __restrict__ Wih1,
        const float* __restrict__ bih1, const float* __restrict__ bhh1,
        float* __restrict__ h2) {
    int wid = (int)((blockIdx.x * 256u + threadIdx.x) >> 6);  // [0, 16384)
    int lane = threadIdx.x & 63;
    int g = wid >> 8, hu = wid & 255;
    int k0 = lane * 4;
    float4 x = *(const float4*)(h1 + g * 256 + k0);
    float ai = dot4(Wih1 + (size_t)hu * 256 + k0, x);
    float ag = dot4(Wih1 + (size_t)(hu + 512) * 256 + k0, x);
    float ao = dot4(Wih1 + (size_t)(hu + 768) * 256 + k0, x);
    #pragma unroll
    for (int msk = 32; msk >= 1; msk >>= 1) {
        ai += __shfl_xor(ai, msk, 64);
        ag += __shfl_xor(ag, msk, 64);
        ao += __shfl_xor(ao, msk, 64);
    }
    if (lane == 0) {
        ai += bih1[hu]       + bhh1[hu];
        ag += bih1[hu + 512] + bhh1[hu + 512];
        ao += bih1[hu + 768] + bhh1[hu + 768];
        float c1 = sigm(ai) * tanhf(ag);
        h2[g * 256 + hu] = sigm(ao) * tanhf(c1);
    }
}

// projection: one wave per (graph, out row), K=256
__global__ __launch_bounds__(256) void k_out(
        const float* __restrict__ h2, const float* __restrict__ Wp,
        const float* __restrict__ bp, float* __restrict__ out) {
    int wid = (int)((blockIdx.x * 256u + threadIdx.x) >> 6);  // [0, 32768)
    int lane = threadIdx.x & 63;
    int g = wid >> 9, r = wid & 511;
    int k0 = lane * 4;
    float4 x = *(const float4*)(h2 + g * 256 + k0);
    float a = dot4(Wp + (size_t)r * 256 + k0, x);
    #pragma unroll
    for (int msk = 32; msk >= 1; msk >>= 1) a += __shfl_xor(a, msk, 64);
    if (lane == 0) out[g * 512 + r] = a + bp[r];
}

// ---------------- launch ----------------

extern "C" void kernel_launch(void* const* d_in, const int* in_sizes, int n_in,
                              void* d_out, int out_size, void* d_ws, size_t ws_size,
                              hipStream_t stream) {
    const float* x     = (const float*)d_in[0];
    const int*   eidx  = (const int*)d_in[1];
    const int*   batch = (const int*)d_in[2];
    const float* W1 = (const float*)d_in[3];  const float* b1 = (const float*)d_in[4];
    const float* W2 = (const float*)d_in[5];  const float* b2 = (const float*)d_in[6];
    const float* W3 = (const float*)d_in[7];  const float* b3 = (const float*)d_in[8];
    const float* Wih0 = (const float*)d_in[9];
    const float* bih0 = (const float*)d_in[11];
    const float* bhh0 = (const float*)d_in[12];
    const float* Wih1 = (const float*)d_in[13];
    const float* bih1 = (const float*)d_in[15];
    const float* bhh1 = (const float*)d_in[16];
    const float* Wp = (const float*)d_in[17]; const float* bp = (const float*)d_in[18];
    float* out = (float*)d_out;

    const int N = in_sizes[0] / 32;
    const int E = in_sizes[1] / 2;
    const int* src = eidx;
    const int* dst = eidx + E;
    const int rowTiles = (N + 63) / 64;

    char* w = (char*)d_ws;
    auto alloc = [&](size_t bytes) {
        char* p = w;
        w += (bytes + 255) & ~(size_t)255;
        return p;
    };
    unsigned short* buf1 = (unsigned short*)alloc((size_t)N * 256 * 2);
    unsigned short* buf2 = (unsigned short*)alloc((size_t)N * 256 * 2);
    unsigned short* Wf2  = (unsigned short*)alloc(256 * 128 * 2);
    unsigned short* Wf3  = (unsigned short*)alloc(512 * 256 * 2);
    int*   indeg  = (int*)alloc((size_t)N * 4);
    int*   off    = (int*)alloc((size_t)(N + 1) * 4);
    int*   cursor = (int*)alloc((size_t)N * 4);
    float* dinv   = (float*)alloc((size_t)N * 4);
    int*   csrc   = (int*)alloc((size_t)(E + 64) * 4);   // +64 pad: agg tail reads
    // xs: prescaled bf16 x (6.4 MB) + pad so `partial` (6.41 MB) fits over it
    unsigned short* xs = (unsigned short*)alloc((size_t)N * 32 * 2 + 65536);
    int*   bsum   = (int*)alloc(8192);
    int*   gstart = (int*)alloc(64 * 4);
    int*   gend   = (int*)alloc(64 * 4);
    float* pooled = (float*)alloc(64 * 512 * 4);
    float* xmean  = (float*)alloc(64 * 512 * 4);
    float* h1buf  = (float*)alloc(64 * 256 * 4);
    float* h2buf  = (float*)alloc(64 * 256 * 4);

    // Aliases (no extra workspace):
    //  partial[rowTiles][2][512] f32 over xs (+pad, dead after aggL1f)
    //  gtile[rowTiles]           i32 over cursor (dead after k_fill)
    float* partial = (float*)xs;
    int*   gtile   = cursor;

    int initTot = 2 * N + 128 + 64 * 512;
    k_init<<<(initTot + 255) / 256, 256, 0, stream>>>(indeg, cursor, gstart, gend, pooled, N);
    k_count<<<(E + 255) / 256, 256, 0, stream>>>(dst, indeg, E, W2, Wf2, W3, Wf3);
    int nb = (N + 1023) / 1024;
    k_scan1<<<nb, 1024, 0, stream>>>(indeg, off, bsum, dinv, x, xs, N);
    k_scan3<<<(N + 1 + 1023) / 1024, 1024, 0, stream>>>(off, bsum, batch, gstart, gend, N, nb);
    k_fill<<<(E + 255) / 256, 256, 0, stream>>>(src, dst, off, cursor, csrc, E);

    int aggBlocks = (N + 3) / 4;

    k_aggL1f<<<aggBlocks, 256, 0, stream>>>(xs, dinv, off, csrc, W1, b1, buf2, N);
    k_aggL2<<<aggBlocks, 256, 0, stream>>>(buf2, dinv, off, csrc, buf1, N);
    k_gemmL2<<<rowTiles, 256, 0, stream>>>(buf1, Wf2, b2, dinv, buf2, N);
    k_aggL3pair<<<aggBlocks, 256, 0, stream>>>(buf2, dinv, off, csrc, buf1, N);
    k_gemmL3pool<<<rowTiles, 256, 0, stream>>>(buf1, Wf3, b3, pooled, partial, gtile, batch, N);

    // head: 64*256 = 16384 waves for lstm0/lstm1, 64*512 = 32768 for out
    k_pool<<<64, 256, 0, stream>>>(pooled, partial, gtile, gstart, gend, xmean);
    k_lstm0<<<4096, 256, 0, stream>>>(xmean, Wih0, bih0, bhh0, h1buf);
    k_lstm1<<<4096, 256, 0, stream>>>(h1buf, Wih1, bih1, bhh1, h2buf);
    k_out<<<8192, 256, 0, stream>>>(h2buf, Wp, bp, out);
}

// Round 10
// 446.131 us; speedup vs baseline: 1.0284x; 1.0284x over previous
//
#include <hip/hip_runtime.h>
#include <math.h>
#include <type_traits>

// ---------- bf16 helpers (intermediate buffers only; I/O is fp32) ----------

__device__ __forceinline__ float bf2f(unsigned short u) {
    union { unsigned int i; float f; } v; v.i = ((unsigned int)u) << 16; return v.f;
}
__device__ __forceinline__ unsigned short f2bf(float f) {
    union { float f_; unsigned int i; } v; v.f_ = f;
    unsigned int x = v.i;
    return (unsigned short)((x + 0x7fffu + ((x >> 16) & 1u)) >> 16);  // RNE
}
__device__ __forceinline__ float sigm(float x) { return 1.f / (1.f + expf(-x)); }

typedef __attribute__((ext_vector_type(8))) short short8;
typedef __attribute__((ext_vector_type(16))) float f32x16;

__device__ __forceinline__ void nt_store8(unsigned short* p, ushort4 o) {
    unsigned long long ob;
    __builtin_memcpy(&ob, &o, 8);
    __builtin_nontemporal_store(ob, (unsigned long long*)p);
}

// ---------------- fused init ----------------

__global__ void k_init(int* __restrict__ indeg, int* __restrict__ cursor,
                       int* __restrict__ gstart, int* __restrict__ gend,
                       float* __restrict__ pooled, int N) {
    int i = blockIdx.x * 256 + threadIdx.x;
    if (i < N) indeg[i] = 0;
    else if (i < 2 * N) cursor[i - N] = 0;
    else if (i < 2 * N + 64) gstart[i - 2 * N] = 0;
    else if (i < 2 * N + 128) gend[i - 2 * N - 64] = 0;
    else if (i < 2 * N + 128 + 64 * 512) pooled[i - 2 * N - 128] = 0.f;
}

// ---------------- weight prep: fragment-major Wf for 32x32x16 MFMA ----------------
// R24: W1 prep restored (aggL1f fusion reverted — it re-staged 16KB W1 per
// agg block x 25000 blocks = 400MB L2 traffic, net -11 us vs split kernels).

template <int K, int NC>
__device__ __forceinline__ void prep_elem(const float* __restrict__ W,
                                          unsigned short* __restrict__ Wf, int idx) {
    constexpr int S = K / 16;
    int lane = idx & 63;
    int ts = idx >> 6;
    int s = ts % S, t = ts / S;
    int n = t * 32 + (lane & 31);
    int kb = s * 16 + (lane >> 5) * 8;
    short8 o;
    #pragma unroll
    for (int j = 0; j < 8; ++j) o[j] = (short)f2bf(W[(size_t)(kb + j) * NC + n]);
    *(short8*)(Wf + (size_t)idx * 8) = o;
}

__global__ void k_count(const int* __restrict__ dst, int* __restrict__ indeg, int E,
                        const float* __restrict__ W1, unsigned short* __restrict__ Wf1,
                        const float* __restrict__ W2, unsigned short* __restrict__ Wf2,
                        const float* __restrict__ W3, unsigned short* __restrict__ Wf3) {
    constexpr int P1 = 32 * 128 / 8, P2 = 128 * 256 / 8, P3 = 256 * 512 / 8;
    int i = blockIdx.x * 256 + threadIdx.x;
    if (i < E) atomicAdd(&indeg[dst[i]], 1);
    if (i < P1) prep_elem<32, 128>(W1, Wf1, i);
    else if (i < P1 + P2) prep_elem<128, 256>(W2, Wf2, i - P1);
    else if (i < P1 + P2 + P3) prep_elem<256, 512>(W3, Wf3, i - P1 - P2);
}

// ---------------- scan + dinv + prescaled xs = bf16(x*dinv) ----------------

__global__ __launch_bounds__(1024) void k_scan1(const int* __restrict__ in, int* __restrict__ out,
                                                int* __restrict__ bsum, float* __restrict__ dinv,
                                                const float* __restrict__ x,
                                                unsigned short* __restrict__ xs,
                                                int N) {
    __shared__ int sd[1024];
    __shared__ float sdv[1024];
    int tid = threadIdx.x;
    int i = blockIdx.x * 1024 + tid;
    int v = (i < N) ? in[i] : 0;
    float dv = rsqrtf((float)v + 1.0f);
    if (i < N) dinv[i] = dv;
    sdv[tid] = dv;
    sd[tid] = v;
    __syncthreads();
    for (int s = 1; s < 1024; s <<= 1) {
        int t = (tid >= s) ? sd[tid - s] : 0;
        __syncthreads();
        sd[tid] += t;
        __syncthreads();
    }
    if (i < N) out[i] = sd[tid] - v;
    if (tid == 1023) bsum[blockIdx.x] = sd[1023];
    // prescale: xs[node] = bf16(x[node] * dinv[node]); 8 ushort4 chunks/node
    int base = blockIdx.x * 1024;
    const float4* x4 = (const float4*)x;
    ushort4* xs4 = (ushort4*)xs;
    #pragma unroll
    for (int rep = 0; rep < 8; ++rep) {
        int j = rep * 1024 + tid;            // [0, 8192): 8 chunks per node
        int node = base + (j >> 3);
        if (node < N) {
            float4 t = x4[(size_t)base * 8 + j];
            float s = sdv[j >> 3];
            ushort4 o;
            o.x = f2bf(t.x * s); o.y = f2bf(t.y * s);
            o.z = f2bf(t.z * s); o.w = f2bf(t.w * s);
            xs4[(size_t)base * 8 + j] = o;   // normal store: random-gathered next
        }
    }
}

// scan3 with folded block-sum reduction (R22: k_scan2 dispatch removed).
// Each block locally reduces bsum[0..nb) for its prefix and the grand total.
__global__ __launch_bounds__(1024) void k_scan3(int* __restrict__ off, const int* __restrict__ bsum,
                                                const int* __restrict__ batch,
                                                int* __restrict__ gstart, int* __restrict__ gend,
                                                int N, int nb) {
    __shared__ int red[32];
    int tid = threadIdx.x, lane = tid & 63, wid = tid >> 6;
    int bid = blockIdx.x;
    int v  = (tid < nb) ? bsum[tid] : 0;     // nb <= 128 < 1024
    int vb = (tid < bid) ? v : 0;
    #pragma unroll
    for (int msk = 1; msk <= 32; msk <<= 1) {
        v  += __shfl_xor(v,  msk, 64);
        vb += __shfl_xor(vb, msk, 64);
    }
    if (lane == 0) { red[wid * 2] = v; red[wid * 2 + 1] = vb; }
    __syncthreads();
    int sAll = 0, sBefore = 0;
    #pragma unroll
    for (int u = 0; u < 16; ++u) { sAll += red[u * 2]; sBefore += red[u * 2 + 1]; }

    int i = bid * 1024 + tid;
    if (i < N) {
        off[i] += sBefore;
        int g = batch[i];
        if (i == 0 || batch[i - 1] != g) gstart[g] = i;
        if (i == N - 1 || batch[i + 1] != g) gend[g] = i + 1;
    } else if (i == N) {
        off[N] = sAll;
    }
}

// fill: csrc only (R20: edge weights folded into prescaled features)
__global__ void k_fill(const int* __restrict__ src, const int* __restrict__ dst,
                       const int* __restrict__ off, int* __restrict__ cursor,
                       int* __restrict__ csrc, int E) {
    int i = blockIdx.x * 256 + threadIdx.x;
    if (i >= E) return;
    int d = dst[i];
    int p = off[d] + atomicAdd(&cursor[d], 1);
    csrc[p] = src[i];
}

// ---------------- aggregation: pure unweighted sum of prescaled rows --------
// agg[d] = dinv[d] * (sum_src hs[src] + hs[d]); OOB tail slots gather the
// node's own row, corrected exactly via corr = 1 - pad. csrc is alloc-padded.
// Outputs NT-stored (consumer = streaming GEMM read; keep L2 for gathers).

// L1: F=32 bf16. 8 edges/iter: lane = grp(8 edges) x cl(8 col-groups of 4).
__global__ __launch_bounds__(256) void k_aggL1(
        const unsigned short* __restrict__ Hin, const float* __restrict__ dinv,
        const int* __restrict__ off, const int* __restrict__ csrc,
        unsigned short* __restrict__ out, int N) {
    constexpr int F = 32;
    int wv = __builtin_amdgcn_readfirstlane(
        (int)((blockIdx.x * 256u + threadIdx.x) >> 6));
    if (wv >= N) return;
    int lane = threadIdx.x & 63;
    int grp = lane >> 3;
    int cl = (lane & 7) * 4;
    int s0 = off[wv], s1 = off[wv + 1];
    int L = s1 - s0;
    float corr = 1.0f - (float)(((L + 7) & ~7) - L);
    float dn = dinv[wv];
    float acc[4] = {0.f, 0.f, 0.f, 0.f};
    for (int e = s0; e < s1; e += 8) {
        int ee = e + grp;
        int ix = csrc[ee];               // padded alloc: safe past s1
        int idx = (ee < s1) ? ix : wv;   // tail gathers own row
        ushort4 v = *(const ushort4*)(Hin + (size_t)idx * F + cl);
        acc[0] += bf2f(v.x); acc[1] += bf2f(v.y);
        acc[2] += bf2f(v.z); acc[3] += bf2f(v.w);
    }
    #pragma unroll
    for (int msk = 8; msk <= 32; msk <<= 1) {
        acc[0] += __shfl_xor(acc[0], msk, 64);
        acc[1] += __shfl_xor(acc[1], msk, 64);
        acc[2] += __shfl_xor(acc[2], msk, 64);
        acc[3] += __shfl_xor(acc[3], msk, 64);
    }
    if (grp == 0) {
        ushort4 sv = *(const ushort4*)(Hin + (size_t)wv * F + cl);
        ushort4 o;
        o.x = f2bf((acc[0] + corr * bf2f(sv.x)) * dn);
        o.y = f2bf((acc[1] + corr * bf2f(sv.y)) * dn);
        o.z = f2bf((acc[2] + corr * bf2f(sv.z)) * dn);
        o.w = f2bf((acc[3] + corr * bf2f(sv.w)) * dn);
        nt_store8(out + (size_t)wv * F + cl, o);
    }
}

// L2: F=128 bf16, pair structure (2 edges per half-wave, ushort4 loads)
__global__ __launch_bounds__(256) void k_aggL2(
        const unsigned short* __restrict__ Hin, const float* __restrict__ dinv,
        const int* __restrict__ off, const int* __restrict__ csrc,
        unsigned short* __restrict__ out, int N) {
    constexpr int F = 128;
    int wv = __builtin_amdgcn_readfirstlane(
        (int)((blockIdx.x * 256u + threadIdx.x) >> 6));
    if (wv >= N) return;
    int lane = threadIdx.x & 63;
    int half = lane >> 5;
    int fb = (lane & 31) * 4;
    int s0 = off[wv], s1 = off[wv + 1];
    int L = s1 - s0;
    float corrTot = 1.0f - (float)(((L + 15) & ~15) - L);
    float acc[4] = {0.f, 0.f, 0.f, 0.f};

    for (int e = s0; e < s1; e += 16) {
        int idx[8];
        #pragma unroll
        for (int j = 0; j < 8; ++j) {
            int ee = e + j * 2 + half;
            int ix = csrc[ee];
            idx[j] = (ee < s1) ? ix : wv;
        }
        ushort4 d0[8];
        #pragma unroll
        for (int j = 0; j < 8; ++j)
            d0[j] = *(const ushort4*)(Hin + (size_t)idx[j] * F + fb);
        #pragma unroll
        for (int j = 0; j < 8; ++j) {
            acc[0] += bf2f(d0[j].x); acc[1] += bf2f(d0[j].y);
            acc[2] += bf2f(d0[j].z); acc[3] += bf2f(d0[j].w);
        }
    }
    #pragma unroll
    for (int k = 0; k < 4; ++k) acc[k] += __shfl_xor(acc[k], 32, 64);

    if (half == 0) {
        float dn = dinv[wv];
        ushort4 sv = *(const ushort4*)(Hin + (size_t)wv * F + fb);
        ushort4 o;
        o.x = f2bf((acc[0] + corrTot * bf2f(sv.x)) * dn);
        o.y = f2bf((acc[1] + corrTot * bf2f(sv.y)) * dn);
        o.z = f2bf((acc[2] + corrTot * bf2f(sv.z)) * dn);
        o.w = f2bf((acc[3] + corrTot * bf2f(sv.w)) * dn);
        nt_store8(out + (size_t)wv * F + fb, o);
    }
}

// L3: F=256 bf16, pair structure. R24: node-range parameterized and launched
// as TWO half dispatches — work-identical, drops the rocprof top-5 cutoff to
// ~35 us so the true #2 kernel becomes visible (all slots were aggL3pair).
__global__ __launch_bounds__(256) void k_aggL3pair(
        const unsigned short* __restrict__ Hin, const float* __restrict__ dinv,
        const int* __restrict__ off, const int* __restrict__ csrc,
        unsigned short* __restrict__ out, int n0, int n1) {
    constexpr int F = 256;
    int wv = __builtin_amdgcn_readfirstlane(
        n0 + (int)((blockIdx.x * 256u + threadIdx.x) >> 6));
    if (wv >= n1) return;
    int lane = threadIdx.x & 63;
    int half = lane >> 5;
    int fb = (lane & 31) * 8;
    int s0 = off[wv], s1 = off[wv + 1];
    int L = s1 - s0;
    float corrTot = 1.0f - (float)(((L + 15) & ~15) - L);
    float acc[8];
    #pragma unroll
    for (int k = 0; k < 8; ++k) acc[k] = 0.f;

    for (int e = s0; e < s1; e += 16) {
        int idx[8];
        #pragma unroll
        for (int j = 0; j < 8; ++j) {
            int ee = e + j * 2 + half;
            int ix = csrc[ee];               // padded alloc: safe past s1
            idx[j] = (ee < s1) ? ix : wv;
        }
        short8 d0[8];
        #pragma unroll
        for (int j = 0; j < 8; ++j)
            d0[j] = *(const short8*)(Hin + (size_t)idx[j] * F + fb);
        #pragma unroll
        for (int j = 0; j < 8; ++j) {
            #pragma unroll
            for (int k = 0; k < 8; ++k)
                acc[k] += bf2f((unsigned short)d0[j][k]);
        }
    }
    #pragma unroll
    for (int k = 0; k < 8; ++k) acc[k] += __shfl_xor(acc[k], 32, 64);

    if (half == 0) {
        float dn = dinv[wv];
        short8 selfv = *(const short8*)(Hin + (size_t)wv * F + fb);
        short8 o;
        #pragma unroll
        for (int k = 0; k < 8; ++k)
            o[k] = (short)f2bf((acc[k] + corrTot * bf2f((unsigned short)selfv[k])) * dn);
        __builtin_nontemporal_store(o, (short8*)(out + (size_t)wv * F + fb));
    }
}

// ---------------- MFMA GEMM: LDS-staged A (swizzled), coalesced B -------------
// POOL=0 epilogue stores relu(.)*dinv[row] (prescaled for next aggregation).
// POOL=1 epilogue: atomic-free register pooling (R18) into partial[tile][2][512].

template <int K, int NC, int POOL>
__device__ __forceinline__ void gemm_body(
        const unsigned short* __restrict__ A, const unsigned short* __restrict__ Wf,
        const float* __restrict__ bias, const float* __restrict__ dinv,
        unsigned short* __restrict__ C,
        float* __restrict__ pooled, float* __restrict__ partial,
        int* __restrict__ gtile, const int* __restrict__ batch, int M) {
    constexpr int S = K / 16;
    constexpr int CPR = K / 8;
    constexpr int NT = NC / 32;
    __shared__ unsigned short sA[64 * K];
    __shared__ int sbat[POOL ? 64 : 1];
    __shared__ float sdv[POOL ? 1 : 64];
    int tid = threadIdx.x, lane = tid & 63, w = tid >> 6;
    int q = lane >> 5, m = lane & 31;
    int row0 = blockIdx.x * 64;

    if (tid < 64) {
        int rr = row0 + tid; if (rr > M - 1) rr = M - 1;
        if (POOL) sbat[tid] = batch[rr];
        else      sdv[tid] = dinv[rr];
    }

    #pragma unroll
    for (int i = 0; i < (64 * CPR) / 256; ++i) {
        int g = i * 256 + tid;
        int mm = g / CPR, kc = g % CPR;
        int grow = row0 + mm; if (grow > M - 1) grow = M - 1;
        short8 v = *(const short8*)(A + (size_t)grow * K + kc * 8);
        int xm = (CPR >= 8) ? (mm & 7) : ((mm >> 1) & 3);
        *(short8*)(sA + (size_t)(mm * CPR + (kc ^ xm)) * 8) = v;
    }
    __syncthreads();

    int gmin = 0; bool fast = false;
    unsigned int selMask = 0;   // bit (half*16+j): row belongs to gmin+1 (not gmin)
    if (POOL) {
        gmin = sbat[0];
        fast = (sbat[63] - gmin) <= 1;
        if (tid == 0) gtile[blockIdx.x] = gmin;
        #pragma unroll
        for (int half = 0; half < 2; ++half) {
            #pragma unroll
            for (int j = 0; j < 16; ++j) {
                int rloc = half * 32 + (j & 3) + 8 * (j >> 2) + 4 * q;
                if (sbat[rloc] != gmin) selMask |= 1u << (half * 16 + j);
            }
        }
    }

    const short8* Wf8 = (const short8*)Wf;
    for (int t = w; t < NT; t += 4) {
        short8 bF[S];
        #pragma unroll
        for (int s = 0; s < S; ++s) bF[s] = Wf8[(t * S + s) * 64 + lane];
        int colBase = t * 32 + m;
        float bv = bias[colBase];
        float p0 = 0.f, p1 = 0.f;   // register pooling: graph gmin / gmin+1
        #pragma unroll
        for (int half = 0; half < 2; ++half) {
            int mrow = half * 32 + m;
            int xm = (CPR >= 8) ? (mrow & 7) : ((mrow >> 1) & 3);
            f32x16 acc;
            #pragma unroll
            for (int j = 0; j < 16; ++j) acc[j] = 0.f;
            #pragma unroll
            for (int s = 0; s < S; ++s) {
                int kc = s * 2 + q;
                short8 aF = *(const short8*)(sA + (size_t)(mrow * CPR + (kc ^ xm)) * 8);
                acc = __builtin_amdgcn_mfma_f32_32x32x16_bf16(aF, bF[s], acc, 0, 0, 0);
            }
            #pragma unroll
            for (int j = 0; j < 16; ++j) {
                int rloc = half * 32 + (j & 3) + 8 * (j >> 2) + 4 * q;
                int row = row0 + rloc;
                if (row < M) {
                    float v = fmaxf(acc[j] + bv, 0.f);
                    if (POOL) {
                        if (fast) {
                            bool sel = (selMask >> (half * 16 + j)) & 1u;
                            p0 += sel ? 0.f : v;
                            p1 += sel ? v : 0.f;
                        } else {
                            // >2 graphs in one 64-row tile: essentially impossible
                            // for this input (nodes/graph ~1563); correctness path.
                            atomicAdd(&pooled[(size_t)sbat[rloc] * NC + colBase], v);
                        }
                    } else {
                        C[(size_t)row * NC + colBase] = f2bf(v * sdv[rloc]);
                    }
                }
            }
        }
        if (POOL) {
            // lanes l and l+32 share colBase -> combine, then one plain store
            p0 += __shfl_xor(p0, 32, 64);
            p1 += __shfl_xor(p1, 32, 64);
            if (q == 0) {
                partial[((size_t)blockIdx.x * 2 + 0) * NC + colBase] = p0;
                partial[((size_t)blockIdx.x * 2 + 1) * NC + colBase] = p1;
            }
        }
    }
}

__global__ __launch_bounds__(256, 2) void k_gemmL1(
        const unsigned short* __restrict__ A, const unsigned short* __restrict__ Wf,
        const float* __restrict__ bias, const float* __restrict__ dinv,
        unsigned short* __restrict__ C, int M) {
    gemm_body<32, 128, 0>(A, Wf, bias, dinv, C, nullptr, nullptr, nullptr, nullptr, M);
}

__global__ __launch_bounds__(256, 2) void k_gemmL2(
        const unsigned short* __restrict__ A, const unsigned short* __restrict__ Wf,
        const float* __restrict__ bias, const float* __restrict__ dinv,
        unsigned short* __restrict__ C, int M) {
    gemm_body<128, 256, 0>(A, Wf, bias, dinv, C, nullptr, nullptr, nullptr, nullptr, M);
}

__global__ __launch_bounds__(256, 2) void k_gemmL3pool(
        const unsigned short* __restrict__ A, const unsigned short* __restrict__ Wf,
        const float* __restrict__ bias, float* __restrict__ pooled,
        float* __restrict__ partial, int* __restrict__ gtile,
        const int* __restrict__ batch, int M) {
    gemm_body<256, 512, 1>(A, Wf, bias, nullptr, nullptr, pooled, partial, gtile, batch, M);
}

// ---------------- head, split for parallelism (R19) ----------------

// partial-tile reduce -> normalized mean xmean[64][512]
__global__ __launch_bounds__(256) void k_pool(
        const float* __restrict__ pooled, const float* __restrict__ partial,
        const int* __restrict__ gtile,
        const int* __restrict__ gstart, const int* __restrict__ gend,
        float* __restrict__ xmean) {
    int g = blockIdx.x, tid = threadIdx.x;
    int gs = gstart[g], ge = gend[g];
    float inv = 1.f / fmaxf((float)(ge - gs), 1.f);
    float a0 = pooled[g * 512 + tid];
    float a1 = pooled[g * 512 + 256 + tid];
    if (ge > gs) {
        int t0 = gs >> 6, t1 = (ge - 1) >> 6;
        for (int t = t0; t <= t1; ++t) {
            unsigned int slot = (unsigned int)(g - gtile[t]);
            if (slot < 2u) {
                const float* p = partial + ((size_t)t * 2 + slot) * 512;
                a0 += p[tid];
                a1 += p[tid + 256];
            }
        }
    }
    xmean[g * 512 + tid]       = a0 * inv;
    xmean[g * 512 + 256 + tid] = a1 * inv;
}

__device__ __forceinline__ float dot8(const float* __restrict__ w,
                                      float4 x0, float4 x1) {
    float4 a = *(const float4*)w, b = *(const float4*)(w + 4);
    return a.x * x0.x + a.y * x0.y + a.z * x0.z + a.w * x0.w +
           b.x * x1.x + b.y * x1.y + b.z * x1.z + b.w * x1.w;
}
__device__ __forceinline__ float dot4(const float* __restrict__ w, float4 x) {
    float4 a = *(const float4*)w;
    return a.x * x.x + a.y * x.y + a.z * x.z + a.w * x.w;
}

// LSTM0: one wave per (graph, hidden unit); gates i,g,o (f dead: c0=0)
__global__ __launch_bounds__(256) void k_lstm0(
        const float* __restrict__ xmean, const float* __restrict__ Wih0,
        const float* __restrict__ bih0, const float* __restrict__ bhh0,
        float* __restrict__ h1) {
    int wid = (int)((blockIdx.x * 256u + threadIdx.x) >> 6);  // [0, 16384)
    int lane = threadIdx.x & 63;
    int g = wid >> 8, hu = wid & 255;
    int k0 = lane * 8;
    const float* xp = xmean + g * 512 + k0;
    float4 x0 = *(const float4*)xp, x1 = *(const float4*)(xp + 4);
    float ai = dot8(Wih0 + (size_t)hu * 512 + k0, x0, x1);
    float ag = dot8(Wih0 + (size_t)(hu + 512) * 512 + k0, x0, x1);
    float ao = dot8(Wih0 + (size_t)(hu + 768) * 512 + k0, x0, x1);
    #pragma unroll
    for (int msk = 32; msk >= 1; msk >>= 1) {
        ai += __shfl_xor(ai, msk, 64);
        ag += __shfl_xor(ag, msk, 64);
        ao += __shfl_xor(ao, msk, 64);
    }
    if (lane == 0) {
        ai += bih0[hu]       + bhh0[hu];
        ag += bih0[hu + 512] + bhh0[hu + 512];
        ao += bih0[hu + 768] + bhh0[hu + 768];
        float c0 = sigm(ai) * tanhf(ag);
        h1[g * 256 + hu] = sigm(ao) * tanhf(c0);
    }
}

// LSTM1: one wave per (graph, hidden unit), K=256
__global__ __launch_bounds__(256) void k_lstm1(
        const float* __restrict__ h1, const float* __restrict__ Wih1,
        const float* __restrict__ bih1, const float* __restrict__ bhh1,
        float* __restrict__ h2) {
    int wid = (int)((blockIdx.x * 256u + threadIdx.x) >> 6);  // [0, 16384)
    int lane = threadIdx.x & 63;
    int g = wid >> 8, hu = wid & 255;
    int k0 = lane * 4;
    float4 x = *(const float4*)(h1 + g * 256 + k0);
    float ai = dot4(Wih1 + (size_t)hu * 256 + k0, x);
    float ag = dot4(Wih1 + (size_t)(hu + 512) * 256 + k0, x);
    float ao = dot4(Wih1 + (size_t)(hu + 768) * 256 + k0, x);
    #pragma unroll
    for (int msk = 32; msk >= 1; msk >>= 1) {
        ai += __shfl_xor(ai, msk, 64);
        ag += __shfl_xor(ag, msk, 64);
        ao += __shfl_xor(ao, msk, 64);
    }
    if (lane == 0) {
        ai += bih1[hu]       + bhh1[hu];
        ag += bih1[hu + 512] + bhh1[hu + 512];
        ao += bih1[hu + 768] + bhh1[hu + 768];
        float c1 = sigm(ai) * tanhf(ag);
        h2[g * 256 + hu] = sigm(ao) * tanhf(c1);
    }
}

// projection: one wave per (graph, out row), K=256
__global__ __launch_bounds__(256) void k_out(
        const float* __restrict__ h2, const float* __restrict__ Wp,
        const float* __restrict__ bp, float* __restrict__ out) {
    int wid = (int)((blockIdx.x * 256u + threadIdx.x) >> 6);  // [0, 32768)
    int lane = threadIdx.x & 63;
    int g = wid >> 9, r = wid & 511;
    int k0 = lane * 4;
    float4 x = *(const float4*)(h2 + g * 256 + k0);
    float a = dot4(Wp + (size_t)r * 256 + k0, x);
    #pragma unroll
    for (int msk = 32; msk >= 1; msk >>= 1) a += __shfl_xor(a, msk, 64);
    if (lane == 0) out[g * 512 + r] = a + bp[r];
}

// ---------------- launch ----------------

extern "C" void kernel_launch(void* const* d_in, const int* in_sizes, int n_in,
                              void* d_out, int out_size, void* d_ws, size_t ws_size,
                              hipStream_t stream) {
    const float* x     = (const float*)d_in[0];
    const int*   eidx  = (const int*)d_in[1];
    const int*   batch = (const int*)d_in[2];
    const float* W1 = (const float*)d_in[3];  const float* b1 = (const float*)d_in[4];
    const float* W2 = (const float*)d_in[5];  const float* b2 = (const float*)d_in[6];
    const float* W3 = (const float*)d_in[7];  const float* b3 = (const float*)d_in[8];
    const float* Wih0 = (const float*)d_in[9];
    const float* bih0 = (const float*)d_in[11];
    const float* bhh0 = (const float*)d_in[12];
    const float* Wih1 = (const float*)d_in[13];
    const float* bih1 = (const float*)d_in[15];
    const float* bhh1 = (const float*)d_in[16];
    const float* Wp = (const float*)d_in[17]; const float* bp = (const float*)d_in[18];
    float* out = (float*)d_out;

    const int N = in_sizes[0] / 32;
    const int E = in_sizes[1] / 2;
    const int* src = eidx;
    const int* dst = eidx + E;
    const int rowTiles = (N + 63) / 64;

    char* w = (char*)d_ws;
    auto alloc = [&](size_t bytes) {
        char* p = w;
        w += (bytes + 255) & ~(size_t)255;
        return p;
    };
    unsigned short* buf1 = (unsigned short*)alloc((size_t)N * 256 * 2);
    unsigned short* buf2 = (unsigned short*)alloc((size_t)N * 256 * 2);
    unsigned short* Wf1  = (unsigned short*)alloc(128 * 32 * 2);
    unsigned short* Wf2  = (unsigned short*)alloc(256 * 128 * 2);
    unsigned short* Wf3  = (unsigned short*)alloc(512 * 256 * 2);
    int*   indeg  = (int*)alloc((size_t)N * 4);
    int*   off    = (int*)alloc((size_t)(N + 1) * 4);
    int*   cursor = (int*)alloc((size_t)N * 4);
    float* dinv   = (float*)alloc((size_t)N * 4);
    int*   csrc   = (int*)alloc((size_t)(E + 64) * 4);   // +64 pad: agg tail reads
    // xs: prescaled bf16 x (6.4 MB) + pad so `partial` (6.41 MB) fits over it
    unsigned short* xs = (unsigned short*)alloc((size_t)N * 32 * 2 + 65536);
    int*   bsum   = (int*)alloc(8192);
    int*   gstart = (int*)alloc(64 * 4);
    int*   gend   = (int*)alloc(64 * 4);
    float* pooled = (float*)alloc(64 * 512 * 4);
    float* xmean  = (float*)alloc(64 * 512 * 4);
    float* h1buf  = (float*)alloc(64 * 256 * 4);
    float* h2buf  = (float*)alloc(64 * 256 * 4);

    // Aliases (no extra workspace):
    //  partial[rowTiles][2][512] f32 over xs (+pad, dead after aggL1)
    //  gtile[rowTiles]           i32 over cursor (dead after k_fill)
    float* partial = (float*)xs;
    int*   gtile   = cursor;

    int initTot = 2 * N + 128 + 64 * 512;
    k_init<<<(initTot + 255) / 256, 256, 0, stream>>>(indeg, cursor, gstart, gend, pooled, N);
    k_count<<<(E + 255) / 256, 256, 0, stream>>>(dst, indeg, E, W1, Wf1, W2, Wf2, W3, Wf3);
    int nb = (N + 1023) / 1024;
    k_scan1<<<nb, 1024, 0, stream>>>(indeg, off, bsum, dinv, x, xs, N);
    k_scan3<<<(N + 1 + 1023) / 1024, 1024, 0, stream>>>(off, bsum, batch, gstart, gend, N, nb);
    k_fill<<<(E + 255) / 256, 256, 0, stream>>>(src, dst, off, cursor, csrc, E);

    int aggBlocks = (N + 3) / 4;

    k_aggL1<<<aggBlocks, 256, 0, stream>>>(xs, dinv, off, csrc, buf1, N);
    k_gemmL1<<<rowTiles, 256, 0, stream>>>(buf1, Wf1, b1, dinv, buf2, N);
    k_aggL2<<<aggBlocks, 256, 0, stream>>>(buf2, dinv, off, csrc, buf1, N);
    k_gemmL2<<<rowTiles, 256, 0, stream>>>(buf1, Wf2, b2, dinv, buf2, N);
    // aggL3 split into two half-node dispatches (observability, R24)
    int half = (N + 1) / 2;
    int aggBlocksA = (half + 3) / 4;
    int aggBlocksB = ((N - half) + 3) / 4;
    k_aggL3pair<<<aggBlocksA, 256, 0, stream>>>(buf2, dinv, off, csrc, buf1, 0, half);
    k_aggL3pair<<<aggBlocksB, 256, 0, stream>>>(buf2, dinv, off, csrc, buf1, half, N);
    k_gemmL3pool<<<rowTiles, 256, 0, stream>>>(buf1, Wf3, b3, pooled, partial, gtile, batch, N);

    // head: 64*256 = 16384 waves for lstm0/lstm1, 64*512 = 32768 for out
    k_pool<<<64, 256, 0, stream>>>(pooled, partial, gtile, gstart, gend, xmean);
    k_lstm0<<<4096, 256, 0, stream>>>(xmean, Wih0, bih0, bhh0, h1buf);
    k_lstm1<<<4096, 256, 0, stream>>>(h1buf, Wih1, bih1, bhh1, h2buf);
    k_out<<<8192, 256, 0, stream>>>(h2buf, Wp, bp, out);
}